// Round 1
// baseline (307.706 us; speedup 1.0000x reference)
//
#include <hip/hip_runtime.h>
#include <hip/hip_bf16.h>

// AdaptiveReLULayer: out[b,n,o] = leaky( sum_i x[b,n,i] * weight[idx[b],i,o] + bias[o], 0.2 )
// B=2048, N=256, IN=256, OUT=256, C=1024.  f32 I/O; bf16 MFMA, f32 accum.
//
// R4 change vs R3 (307us, HBM 39%, Occ 22%, LDS 64KB -> 2 blocks/CU):
// latency-bound, not roofline-bound. Convert f32->bf16 AT STAGE TIME via
// register staging (global->reg->cvt->LDS), store B transposed [o][k]:
//   * LDS 64KB -> 32KB (bf16 tiles)  => 2 -> ~4-5 blocks/CU occupancy
//   * B fragment read: 32x ds_read_b32 + 16 pk2  ->  1x ds_read_b128 (no cvt)
//   * inner loop: 8 ds_read_b128 + 16 MFMA per lane per K-step, zero pk2
//   * ONE raw barrier per K-step (lgkmcnt(0) only; global loads for t+2 stay
//     in flight across it -- reg staging makes counted-vmcnt automatic)
// Tiles stored as 64 row-pairs x 128B, XOR swizzle chunk ^= (rowpair&7).

#define N_DIM 256
#define K_DIM 256
#define O_DIM 256
#define BK 32

typedef __attribute__((ext_vector_type(8))) __bf16 bf16x8;
typedef __attribute__((ext_vector_type(4))) float f32x4;
typedef __attribute__((ext_vector_type(4))) unsigned int u32x4;
typedef __attribute__((ext_vector_type(2))) unsigned int u32x2;

__device__ __forceinline__ f32x4 MFMA(u32x4 a, u32x4 b, f32x4 c) {
    return __builtin_amdgcn_mfma_f32_16x16x32_bf16(
        __builtin_bit_cast(bf16x8, a), __builtin_bit_cast(bf16x8, b), c, 0, 0, 0);
}

__device__ __forceinline__ unsigned pk2(float a, float b) {
    __hip_bfloat16 ha = __float2bfloat16(a);
    __hip_bfloat16 hb = __float2bfloat16(b);
    unsigned short sa, sb;
    __builtin_memcpy(&sa, &ha, 2);
    __builtin_memcpy(&sb, &hb, 2);
    return (unsigned)sa | ((unsigned)sb << 16);
}

// bf16 tile stored as 64 row-pairs x 128B.  (row, k) -> byte offset.
// chunk(16B) index pre-swizzle = (row&1)*4 + (k>>3), XOR'd with (row>>1)&7.
__device__ __forceinline__ int swz(int row, int k) {
    const int rp = row >> 1;
    const int ch = (((row & 1) << 2) + (k >> 3)) ^ (rp & 7);
    return rp * 128 + ch * 16 + (k & 7) * 2;
}

__global__ __launch_bounds__(256) void argemm_kernel(
    const float* __restrict__ x,
    const int* __restrict__ idx,
    const float* __restrict__ w,
    const float* __restrict__ bias,
    float* __restrict__ out)
{
    __shared__ __align__(16) char lds[32768];  // A dbuf 2x8KB | B^T dbuf 2x8KB

    const int tid = threadIdx.x;
    const int l   = tid & 63;
    const int wid = tid >> 6;
    const int wr  = wid >> 1;   // wave row (0..1) -> 64-row half
    const int wc  = wid & 1;    // wave col (0..1) -> 64-col half

    // XCD-chunked block swizzle (gridDim.x % 8 == 0)
    const unsigned bid     = blockIdx.x;
    const unsigned chunk   = gridDim.x >> 3;
    const unsigned logical = (bid & 7u) * chunk + (bid >> 3);
    const int b    = (int)(logical >> 2);
    const int tpos = (int)(logical & 3u);
    const int n0   = (tpos >> 1) * 128;
    const int o0   = (tpos & 1) * 128;

    const int c = idx[b];
    const float* xb = x + (size_t)b * (N_DIM * K_DIM);
    const float* wb = w + (size_t)c * (K_DIM * O_DIM);

    // ---- staging maps ----
    // A: thread covers rows wid*32+q*8+(l>>3), k-chunk (l&7)*4..+3
    const int lr3 = l >> 3, kc = l & 7;
    int gA[4], aW[4];
#pragma unroll
    for (int q = 0; q < 4; ++q) {
        const int rA = wid * 32 + q * 8 + lr3;         // 0..127
        gA[q] = (n0 + rA) * K_DIM + kc * 4;            // f32 elem offset
        aW[q] = swz(rA, kc * 4);                       // LDS byte (b64 write)
    }
    // B: thread covers k rows kq*4+dk, o-cols m4..m4+3; written TRANSPOSED
    const int kq = tid >> 5;          // 0..7
    const int m4 = (tid & 31) * 4;    // o 0..124
    int gB[4], bW[4];
#pragma unroll
    for (int dk = 0; dk < 4; ++dk)
        gB[dk] = (kq * 4 + dk) * O_DIM + o0 + m4;      // f32 elem offset
#pragma unroll
    for (int j = 0; j < 4; ++j)
        bW[j] = 16384 + swz(m4 + j, kq * 4);           // B^T[o][k] byte

    // ---- fragment read addresses (constant across K-steps; g fixed/lane) ----
    const int g = l >> 4;   // 0..3 (k-subgroup)
    const int i = l & 15;   // 0..15
    int aR[4], bR[4];
#pragma unroll
    for (int m = 0; m < 4; ++m) aR[m] = swz(wr * 64 + m * 16 + i, g * 8);
#pragma unroll
    for (int n = 0; n < 4; ++n) bR[n] = 16384 + swz(wc * 64 + n * 16 + i, g * 8);

    f32x4 ra[4], rb[4];   // staged registers (one tile in flight)

    auto issue = [&](int t) {
#pragma unroll
        for (int q = 0; q < 4; ++q)
            ra[q] = *(const f32x4*)(xb + gA[q] + t * BK);
#pragma unroll
        for (int dk = 0; dk < 4; ++dk)
            rb[dk] = *(const f32x4*)(wb + gB[dk] + t * (BK * O_DIM));
    };
    // cvt f32->bf16 and write LDS (compiler inserts the counted vmcnt waits)
    auto flush = [&](int buf) {
        char* base = (char*)lds + buf * 8192;
#pragma unroll
        for (int q = 0; q < 4; ++q) {
            u32x2 p;
            p.x = pk2(ra[q].x, ra[q].y);
            p.y = pk2(ra[q].z, ra[q].w);
            *(u32x2*)(base + aW[q]) = p;               // A[row][k], k-contig
        }
#pragma unroll
        for (int j = 0; j < 4; ++j) {
            u32x2 p;                                    // pack along k
            p.x = pk2(rb[0][j], rb[1][j]);
            p.y = pk2(rb[2][j], rb[3][j]);
            *(u32x2*)(base + bW[j]) = p;               // B^T[o][k], k-contig
        }
    };

    f32x4 acc[4][4];
#pragma unroll
    for (int m = 0; m < 4; ++m)
#pragma unroll
        for (int n = 0; n < 4; ++n)
            acc[m][n] = (f32x4){0.f, 0.f, 0.f, 0.f};

    // prologue: tile0 -> LDS, tile1 loads in flight across the barrier
    issue(0);
    flush(0);
    issue(1);
    asm volatile("s_waitcnt lgkmcnt(0)" ::: "memory");
    __builtin_amdgcn_sched_barrier(0);
    __builtin_amdgcn_s_barrier();

#pragma unroll
    for (int t = 0; t < 8; ++t) {
        const int cur = t & 1;
        const char* base = (const char*)lds + cur * 8192;

        u32x4 af[4];
#pragma unroll
        for (int m = 0; m < 4; ++m)
            af[m] = *(const u32x4*)(base + aR[m]);     // 8 bf16, ready to MFMA
#pragma unroll
        for (int n = 0; n < 4; ++n) {
            const u32x4 bq = *(const u32x4*)(base + bR[n]);
#pragma unroll
            for (int m = 0; m < 4; ++m)
                acc[m][n] = MFMA(af[m], bq, acc[m][n]);
        }

        if (t < 7) {
            flush(cur ^ 1);          // cvt+write tile t+1 (loads issued last iter)
            if (t < 6) issue(t + 2); // next tile's loads: in flight across barrier
            // LDS ops drained (reads retired + writes visible), globals NOT:
            asm volatile("s_waitcnt lgkmcnt(0)" ::: "memory");
            __builtin_amdgcn_sched_barrier(0);
            __builtin_amdgcn_s_barrier();
        }
    }

    // ---- epilogue: bias + LeakyReLU(0.2), f32 store ----
    float biasf[4];
#pragma unroll
    for (int n = 0; n < 4; ++n)
        biasf[n] = bias[o0 + wc * 64 + n * 16 + i];

    float* ob = out + (size_t)b * (N_DIM * O_DIM);
#pragma unroll
    for (int m = 0; m < 4; ++m) {
#pragma unroll
        for (int r = 0; r < 4; ++r) {
            const int row = n0 + wr * 64 + m * 16 + g * 4 + r;
#pragma unroll
            for (int n = 0; n < 4; ++n) {
                float v = acc[m][n][r] + biasf[n];
                v = (v >= 0.f) ? v : 0.2f * v;
                ob[row * O_DIM + o0 + wc * 64 + n * 16 + i] = v;
            }
        }
    }
}

extern "C" void kernel_launch(void* const* d_in, const int* in_sizes, int n_in,
                              void* d_out, int out_size, void* d_ws, size_t ws_size,
                              hipStream_t stream) {
    const float* x    = (const float*)d_in[0];
    const int*   idx  = (const int*)d_in[1];
    const float* w    = (const float*)d_in[2];
    const float* bias = (const float*)d_in[3];
    float*       out  = (float*)d_out;
    (void)d_ws; (void)ws_size; (void)n_in; (void)out_size;

    const int B = in_sizes[1];          // 2048
    dim3 grid((unsigned)(B * 4)), block(256);
    hipLaunchKernelGGL(argemm_kernel, grid, block, 0, stream, x, idx, w, bias, out);
}